// Round 6
// baseline (211.469 us; speedup 1.0000x reference)
//
#include <hip/hip_runtime.h>
#include <math.h>

// Problem constants
#define BB 128
#define ND 32
#define NIJ 16384
#define EPS2 0.25f
#define EPS4 0.0625f

// Tiling: R3 structure, halved tile for occupancy
#define TIJ 32
#define NBLK (NIJ / TIJ)        // 512 blocks (2/CU)
#define NTHR 512
#define QN 8                    // ij-lanes per b-pair group
#define IJT (TIJ / QN)          // 4 ij per thread
#define ROWF 132                // 128 coef floats + 4 pad

// LDS (floats): region0 [0,4608) = coef[32][132] (phases 1-2), then stage
// rows of stride 36 (num[128][32]+den interleaved) for the epilogue.
#define STG_ROW 36
#define CC_OFF  4608
#define LAM_OFF 4640
#define LDS_FL  4672            // 18.7 KB -> LDS allows many blocks/CU

// part layout per block (packed, full lines): num[128][32] @0, den[128] @4096
#define PART_STRIDE 4224
#define DEN_OFF 4096

__global__ __launch_bounds__(NTHR, 4) void gmm_fused(
    const float* __restrict__ Xg,
    const float* __restrict__ tptr,
    const float* __restrict__ Mu0, const float* __restrict__ Mu1,
    const float* __restrict__ S0,  const float* __restrict__ S1,
    const float* __restrict__ Lam,
    float* __restrict__ part)
{
    __shared__ __align__(16) float lds[LDS_FL];

    const int tid  = threadIdx.x;
    const int blk  = blockIdx.x;
    const int ij0g = blk * TIJ;
    const float t   = tptr[0];
    const float omt = 1.0f - t;

    // ---- X for this thread's two b values -> registers (issue early) ----
    const int g  = tid >> 3;       // 0..63: b-pair index
    const int q  = tid & 7;        // ij-lane
    const int b0 = 2 * g;
    const int b1 = 2 * g + 1;
    float x0[ND], x1[ND];
#pragma unroll
    for (int c = 0; c < 8; ++c) {
        const float4 v0 = ((const float4*)(Xg + b0 * ND))[c];
        const float4 v1 = ((const float4*)(Xg + b1 * ND))[c];
        x0[4*c+0] = v0.x; x0[4*c+1] = v0.y; x0[4*c+2] = v0.z; x0[4*c+3] = v0.w;
        x1[4*c+0] = v1.x; x1[4*c+1] = v1.y; x1[4*c+2] = v1.z; x1[4*c+3] = v1.w;
    }

    // ---- Phase 1: per-(ij, n) coefficients into LDS ----
    // 32 ij * 32 n = 1024 pairs over 512 threads -> 2 each
#pragma unroll
    for (int k = 0; k < (TIJ * ND) / NTHR; ++k) {
        const int idx = tid + k * NTHR;
        const int ijl = idx >> 5;          // 0..31
        const int n   = idx & 31;
        const int ij  = ij0g + ijl;
        const int i   = ij >> 7;
        const int j   = ij & 127;
        const float s0  = S0[i * ND + n];
        const float s1  = S1[j * ND + n];
        const float mu0 = Mu0[i * ND + n];
        const float mu1 = Mu1[j * ND + n];
        const float Ds  = sqrtf(4.0f * s0 * s1 + EPS4);
        const float Cs  = 0.5f * (Ds - EPS2);
        const float Sigma = omt * omt * s0 + t * t * s1
                          + 2.0f * t * omt * Cs + EPS2 * t * omt;
        const float St  = (t * s1 + omt * Cs) - (omt * s0 + t * Cs) - EPS2 * t;
        const float Mut = omt * mu0 + t * mu1;
        const float v   = mu1 - mu0;
        const float invS = 1.0f / Sigma;
        const float Kf  = St * invS;
        const float cA  = -0.5f * invS;
        const float cB  = Mut * invS;
        // coef row: [cA 32 | cB 32 | K 32 | KV 32 | pad 4]; bank (4*ijl+n)%32 -> 2-way
        lds[ijl * ROWF + n]      = cA;
        lds[ijl * ROWF + 32 + n] = cB;
        lds[ijl * ROWF + 64 + n] = Kf;
        lds[ijl * ROWF + 96 + n] = v - Kf * Mut;
        float cc = cA * Mut * Mut - 0.5f * __logf(Sigma);
        cc += __shfl_xor(cc, 1);
        cc += __shfl_xor(cc, 2);
        cc += __shfl_xor(cc, 4);
        cc += __shfl_xor(cc, 8);
        cc += __shfl_xor(cc, 16);
        if (n == 0) lds[CC_OFF + ijl] = cc;
    }
    if (tid < TIJ) lds[LAM_OFF + tid] = Lam[ij0g + tid];

    float num0[ND], num1[ND];
#pragma unroll
    for (int n = 0; n < ND; ++n) { num0[n] = 0.0f; num1[n] = 0.0f; }
    float den0 = 0.0f, den1 = 0.0f;

    __syncthreads();

    // ---- Phase 2: thread does 2 b x 4 ij; row reads are 8-lane broadcasts ----
#pragma unroll
    for (int it = 0; it < IJT; ++it) {
        const int ijl = q + it * QN;       // 8 distinct rows per wave, disjoint banks
        const float* __restrict__ row = &lds[ijl * ROWF];
        const float cc0 = lds[CC_OFF + ijl];
        float lw0a = cc0, lw0b = 0.0f, lw1a = cc0, lw1b = 0.0f;
#pragma unroll
        for (int nc = 0; nc < 8; ++nc) {
            const float4 a  = *(const float4*)&row[nc * 4];
            const float4 bq = *(const float4*)&row[32 + nc * 4];
#define LOGW_STEP(comp, nn) \
            lw0a = fmaf(fmaf(a.comp, x0[nn], bq.comp), x0[nn], lw0a); \
            lw1a = fmaf(fmaf(a.comp, x1[nn], bq.comp), x1[nn], lw1a);
#define LOGW_STEPB(comp, nn) \
            lw0b = fmaf(fmaf(a.comp, x0[nn], bq.comp), x0[nn], lw0b); \
            lw1b = fmaf(fmaf(a.comp, x1[nn], bq.comp), x1[nn], lw1b);
            LOGW_STEP(x, nc*4+0) LOGW_STEPB(y, nc*4+1)
            LOGW_STEP(z, nc*4+2) LOGW_STEPB(w, nc*4+3)
#undef LOGW_STEP
#undef LOGW_STEPB
        }
        const float lam = lds[LAM_OFF + ijl];
        float lw0 = lw0a + lw0b;
        float lw1 = lw1a + lw1b;
        lw0 = fminf(fmaxf(lw0, -50.0f), 50.0f);
        lw1 = fminf(fmaxf(lw1, -50.0f), 50.0f);
        const float w0 = __expf(lw0) * lam;
        const float w1 = __expf(lw1) * lam;
        den0 += w0;
        den1 += w1;
#pragma unroll
        for (int nc = 0; nc < 8; ++nc) {
            const float4 kk = *(const float4*)&row[64 + nc * 4];
            const float4 kv = *(const float4*)&row[96 + nc * 4];
#define NUM_STEP(comp, nn) \
            num0[nn] = fmaf(w0, fmaf(kk.comp, x0[nn], kv.comp), num0[nn]); \
            num1[nn] = fmaf(w1, fmaf(kk.comp, x1[nn], kv.comp), num1[nn]);
            NUM_STEP(x, nc*4+0) NUM_STEP(y, nc*4+1)
            NUM_STEP(z, nc*4+2) NUM_STEP(w, nc*4+3)
#undef NUM_STEP
        }
    }

    // ---- Reduce across the 8 q-lanes (consecutive lanes, same wave) ----
#pragma unroll
    for (int m = 1; m <= 4; m <<= 1) {
        den0 += __shfl_xor(den0, m);
        den1 += __shfl_xor(den1, m);
#pragma unroll
        for (int n = 0; n < ND; ++n) {
            num0[n] += __shfl_xor(num0[n], m);
            num1[n] += __shfl_xor(num1[n], m);
        }
    }

    __syncthreads();   // all phase-2 LDS reads done before stage overwrites coef

    // ---- Stage into LDS (stride-36 rows: bank = (4b+n)%32 -> 2-way) ----
    if (q == 0) {
#pragma unroll
        for (int c = 0; c < 8; ++c) {
            *(float4*)&lds[b0 * STG_ROW + 4 * c] =
                make_float4(num0[4*c], num0[4*c+1], num0[4*c+2], num0[4*c+3]);
            *(float4*)&lds[b1 * STG_ROW + 4 * c] =
                make_float4(num1[4*c], num1[4*c+1], num1[4*c+2], num1[4*c+3]);
        }
        lds[b0 * STG_ROW + 32] = den0;
        lds[b1 * STG_ROW + 32] = den1;
    }

    __syncthreads();

    // ---- Coalesced packed block store: 4224 floats, full 128B lines ----
    float* __restrict__ dstg = part + (size_t)blk * PART_STRIDE;
    for (int k = tid; k < PART_STRIDE / 4; k += NTHR) {
        const int p = 4 * k;
        float4 val;
        if (p < DEN_OFF) {
            const int b = p >> 5;
            const int n = p & 31;
            val = *(const float4*)&lds[b * STG_ROW + n];
        } else {
            const int d = p - DEN_OFF;      // den[d..d+3]
            val = make_float4(lds[(d + 0) * STG_ROW + 32],
                              lds[(d + 1) * STG_ROW + 32],
                              lds[(d + 2) * STG_ROW + 32],
                              lds[(d + 3) * STG_ROW + 32]);
        }
        *(float4*)(dstg + p) = val;
    }
}

// One block per b: sum partials over the 512 blocks (coalesced full-line
// reads: lane = n index within a block's num slice), divide, store out.
__global__ __launch_bounds__(512) void gmm_reduce(
    const float* __restrict__ part,
    float* __restrict__ out)
{
    const int b    = blockIdx.x;
    const int lane = threadIdx.x & 63;
    const int w    = threadIdx.x >> 6;       // 8 waves

    // lane<32: num[b][lane]; lane==32: den[b]; others idle
    const int off  = (lane < 32) ? (b * 32 + lane) : (DEN_OFF + b);
    const bool act = (lane <= 32);

    float a0 = 0.0f, a1 = 0.0f, a2 = 0.0f, a3 = 0.0f;
#pragma unroll
    for (int gg = 0; gg < 16; ++gg) {
        const int blk = w + gg * 32;
        if (act) {
            a0 += part[(size_t)(blk +  0) * PART_STRIDE + off];
            a1 += part[(size_t)(blk +  8) * PART_STRIDE + off];
            a2 += part[(size_t)(blk + 16) * PART_STRIDE + off];
            a3 += part[(size_t)(blk + 24) * PART_STRIDE + off];
        }
    }
    const float acc = (a0 + a1) + (a2 + a3);

    __shared__ float red[8][36];
    if (lane <= 32) red[w][lane] = acc;
    __syncthreads();

    if (threadIdx.x < 32) {
        float num = 0.0f, den = 0.0f;
#pragma unroll
        for (int k = 0; k < 8; ++k) {
            num += red[k][threadIdx.x];
            den += red[k][32];
        }
        out[b * 32 + threadIdx.x] = num / den;
    }
}

extern "C" void kernel_launch(void* const* d_in, const int* in_sizes, int n_in,
                              void* d_out, int out_size, void* d_ws, size_t ws_size,
                              hipStream_t stream)
{
    const float* X   = (const float*)d_in[0];
    const float* t   = (const float*)d_in[1];
    const float* Mu0 = (const float*)d_in[2];
    const float* Mu1 = (const float*)d_in[3];
    const float* S0  = (const float*)d_in[4];
    const float* S1  = (const float*)d_in[5];
    const float* Lam = (const float*)d_in[6];
    float* out  = (float*)d_out;
    float* part = (float*)d_ws;             // NBLK * PART_STRIDE floats (8.65 MB)

    gmm_fused<<<NBLK, NTHR, 0, stream>>>(X, t, Mu0, Mu1, S0, S1, Lam, part);
    gmm_reduce<<<BB, 512, 0, stream>>>(part, out);
}

// Round 7
// 87.460 us; speedup vs baseline: 2.4179x; 2.4179x over previous
//
#include <hip/hip_runtime.h>
#include <math.h>

// Problem constants
#define BB 128
#define ND 32
#define NIJ 16384
#define EPS2 0.25f
#define EPS4 0.0625f

// Tiling: 1024 blocks = 512 ij-slices x 2 b-halves; 256 thr = 64 b x 4 q
#define TIJ 32
#define NSLICE (NIJ / TIJ)      // 512
#define NBLK (NSLICE * 2)       // 1024
#define NTHR 256
#define BH 64                   // b per block (half batch)
#define ROWF 132                // coef row: cA32|cB32|K32|KV32|pad4

// LDS layout (floats)
#define XS_OFF  4224            // X stage [64][36]
#define CC_OFF  6528
#define LAM_OFF 6560
#define LDS_FL  6592            // 26.4 KB -> 4 blocks/CU by LDS
#define STG_ROW 36              // epilogue stage aliases coef region [0,2304)

// part layout per block (packed): num[64][32] @0, den[64] @2048
#define PART_STRIDE 2112
#define DEN_OFF_P 2048

__global__ __launch_bounds__(NTHR, 3) void gmm_fused(
    const float* __restrict__ Xg,
    const float* __restrict__ tptr,
    const float* __restrict__ Mu0, const float* __restrict__ Mu1,
    const float* __restrict__ S0,  const float* __restrict__ S1,
    const float* __restrict__ Lam,
    float* __restrict__ part)
{
    __shared__ __align__(16) float lds[LDS_FL];

    const int tid   = threadIdx.x;
    const int blk   = blockIdx.x;
    const int slice = blk & (NSLICE - 1);
    const int half  = blk >> 9;            // 0 or 1
    const int ij0g  = slice * TIJ;
    const float t   = tptr[0];
    const float omt = 1.0f - t;

    // ---- Phase 1a: X half-batch -> LDS stage [64][36] (2-way banks) ----
#pragma unroll
    for (int k = 0; k < (BH * ND) / NTHR; ++k) {
        const int idx = tid + k * NTHR;    // 2048 floats
        lds[XS_OFF + (idx >> 5) * STG_ROW + (idx & 31)] =
            Xg[half * (BH * ND) + idx];
    }

    // ---- Phase 1b: per-(ij, n) coefficients into LDS ----
    // 32 ij * 32 n = 1024 pairs over 256 threads -> 4 each
#pragma unroll
    for (int k = 0; k < (TIJ * ND) / NTHR; ++k) {
        const int idx = tid + k * NTHR;
        const int ijl = idx >> 5;          // 0..31
        const int n   = idx & 31;
        const int ij  = ij0g + ijl;
        const int i   = ij >> 7;
        const int j   = ij & 127;
        const float s0  = S0[i * ND + n];
        const float s1  = S1[j * ND + n];
        const float mu0 = Mu0[i * ND + n];
        const float mu1 = Mu1[j * ND + n];
        const float Ds  = sqrtf(4.0f * s0 * s1 + EPS4);
        const float Cs  = 0.5f * (Ds - EPS2);
        const float Sigma = omt * omt * s0 + t * t * s1
                          + 2.0f * t * omt * Cs + EPS2 * t * omt;
        const float St  = (t * s1 + omt * Cs) - (omt * s0 + t * Cs) - EPS2 * t;
        const float Mut = omt * mu0 + t * mu1;
        const float v   = mu1 - mu0;
        const float invS = 1.0f / Sigma;
        const float Kf  = St * invS;
        const float cA  = -0.5f * invS;
        const float cB  = Mut * invS;
        lds[ijl * ROWF + n]      = cA;
        lds[ijl * ROWF + 32 + n] = cB;
        lds[ijl * ROWF + 64 + n] = Kf;
        lds[ijl * ROWF + 96 + n] = v - Kf * Mut;
        float cc = cA * Mut * Mut - 0.5f * __logf(Sigma);
        cc += __shfl_xor(cc, 1);
        cc += __shfl_xor(cc, 2);
        cc += __shfl_xor(cc, 4);
        cc += __shfl_xor(cc, 8);
        cc += __shfl_xor(cc, 16);
        if (n == 0) lds[CC_OFF + ijl] = cc;
    }
    if (tid < TIJ) lds[LAM_OFF + tid] = Lam[ij0g + tid];

    __syncthreads();

    // ---- X row for this thread's b -> registers (16-lane bcast, 2-way) ----
    const int bl = tid >> 2;      // 0..63 local b
    const int q  = tid & 3;       // ij-lane
    float x[ND];
#pragma unroll
    for (int c = 0; c < 8; ++c) {
        const float4 v4 = *(const float4*)&lds[XS_OFF + bl * STG_ROW + 4 * c];
        x[4*c+0] = v4.x; x[4*c+1] = v4.y; x[4*c+2] = v4.z; x[4*c+3] = v4.w;
    }

    float num[ND];
#pragma unroll
    for (int n = 0; n < ND; ++n) num[n] = 0.0f;
    float den = 0.0f;

    // ---- Phase 2: thread does 1 b x 8 ij; row reads are 16-lane bcast ----
#pragma unroll
    for (int it = 0; it < TIJ / 4; ++it) {
        const int ijl = q + it * 4;        // 4 distinct rows/wave, bank-disjoint
        const float* __restrict__ row = &lds[ijl * ROWF];
        const float cc0 = lds[CC_OFF + ijl];
        float lwa = cc0, lwb = 0.0f;
#pragma unroll
        for (int nc = 0; nc < 8; ++nc) {
            const float4 a  = *(const float4*)&row[nc * 4];
            const float4 bq = *(const float4*)&row[32 + nc * 4];
            lwa = fmaf(fmaf(a.x, x[nc*4+0], bq.x), x[nc*4+0], lwa);
            lwb = fmaf(fmaf(a.y, x[nc*4+1], bq.y), x[nc*4+1], lwb);
            lwa = fmaf(fmaf(a.z, x[nc*4+2], bq.z), x[nc*4+2], lwa);
            lwb = fmaf(fmaf(a.w, x[nc*4+3], bq.w), x[nc*4+3], lwb);
        }
        float lw = lwa + lwb;
        lw = fminf(fmaxf(lw, -50.0f), 50.0f);
        const float w = __expf(lw) * lds[LAM_OFF + ijl];
        den += w;
#pragma unroll
        for (int nc = 0; nc < 8; ++nc) {
            const float4 kk = *(const float4*)&row[64 + nc * 4];
            const float4 kv = *(const float4*)&row[96 + nc * 4];
            num[nc*4+0] = fmaf(w, fmaf(kk.x, x[nc*4+0], kv.x), num[nc*4+0]);
            num[nc*4+1] = fmaf(w, fmaf(kk.y, x[nc*4+1], kv.y), num[nc*4+1]);
            num[nc*4+2] = fmaf(w, fmaf(kk.z, x[nc*4+2], kv.z), num[nc*4+2]);
            num[nc*4+3] = fmaf(w, fmaf(kk.w, x[nc*4+3], kv.w), num[nc*4+3]);
        }
    }

    // ---- Reduce across the 4 q-lanes (lane bits 0-1) ----
#pragma unroll
    for (int m = 1; m <= 2; m <<= 1) {
        den += __shfl_xor(den, m);
#pragma unroll
        for (int n = 0; n < ND; ++n) num[n] += __shfl_xor(num[n], m);
    }

    __syncthreads();   // phase-2 LDS reads done before stage overwrites coef

    // ---- Stage into LDS [64][36] rows (2-way banks) ----
    if (q == 0) {
#pragma unroll
        for (int c = 0; c < 8; ++c) {
            *(float4*)&lds[bl * STG_ROW + 4 * c] =
                make_float4(num[4*c], num[4*c+1], num[4*c+2], num[4*c+3]);
        }
        lds[bl * STG_ROW + 32] = den;
    }

    __syncthreads();

    // ---- Coalesced packed block store: 2112 floats, full 128B lines ----
    float* __restrict__ dstg = part + (size_t)blk * PART_STRIDE;
#pragma unroll
    for (int k = 0; k < 3; ++k) {
        const int kk = tid + k * NTHR;     // 0..767 (528 used)
        if (kk < PART_STRIDE / 4) {
            const int p = 4 * kk;
            float4 val;
            if (p < DEN_OFF_P) {
                val = *(const float4*)&lds[(p >> 5) * STG_ROW + (p & 31)];
            } else {
                const int d = p - DEN_OFF_P;
                val = make_float4(lds[(d + 0) * STG_ROW + 32],
                                  lds[(d + 1) * STG_ROW + 32],
                                  lds[(d + 2) * STG_ROW + 32],
                                  lds[(d + 3) * STG_ROW + 32]);
            }
            *(float4*)(dstg + p) = val;
        }
    }
}

// One block per b: sum the 512 slice-partials of its half, divide, store.
__global__ __launch_bounds__(512) void gmm_reduce(
    const float* __restrict__ part,
    float* __restrict__ out)
{
    const int b    = blockIdx.x;            // 0..127
    const int half = b >> 6;
    const int bl   = b & 63;
    const int lane = threadIdx.x & 63;
    const int w    = threadIdx.x >> 6;      // 8 waves

    const size_t base = (size_t)half * NSLICE * PART_STRIDE;
    const int off  = (lane < 32) ? (bl * 32 + lane) : (DEN_OFF_P + bl);
    const bool act = (lane <= 32);

    float a0 = 0.0f, a1 = 0.0f, a2 = 0.0f, a3 = 0.0f;
#pragma unroll
    for (int gg = 0; gg < 16; ++gg) {
        const int s = w + gg * 32;
        if (act) {
            a0 += part[base + (size_t)(s +  0) * PART_STRIDE + off];
            a1 += part[base + (size_t)(s +  8) * PART_STRIDE + off];
            a2 += part[base + (size_t)(s + 16) * PART_STRIDE + off];
            a3 += part[base + (size_t)(s + 24) * PART_STRIDE + off];
        }
    }
    const float acc = (a0 + a1) + (a2 + a3);

    __shared__ float red[8][36];
    if (lane <= 32) red[w][lane] = acc;
    __syncthreads();

    if (threadIdx.x < 32) {
        float num = 0.0f, den = 0.0f;
#pragma unroll
        for (int k = 0; k < 8; ++k) {
            num += red[k][threadIdx.x];
            den += red[k][32];
        }
        out[b * 32 + threadIdx.x] = num / den;
    }
}

extern "C" void kernel_launch(void* const* d_in, const int* in_sizes, int n_in,
                              void* d_out, int out_size, void* d_ws, size_t ws_size,
                              hipStream_t stream)
{
    const float* X   = (const float*)d_in[0];
    const float* t   = (const float*)d_in[1];
    const float* Mu0 = (const float*)d_in[2];
    const float* Mu1 = (const float*)d_in[3];
    const float* S0  = (const float*)d_in[4];
    const float* S1  = (const float*)d_in[5];
    const float* Lam = (const float*)d_in[6];
    float* out  = (float*)d_out;
    float* part = (float*)d_ws;             // NBLK * PART_STRIDE floats (8.65 MB)

    gmm_fused<<<NBLK, NTHR, 0, stream>>>(X, t, Mu0, Mu1, S0, S1, Lam, part);
    gmm_reduce<<<BB, 512, 0, stream>>>(part, out);
}

// Round 8
// 83.350 us; speedup vs baseline: 2.5371x; 1.0493x over previous
//
#include <hip/hip_runtime.h>
#include <math.h>

// Problem constants
#define BB 128
#define ND 32
#define NIJ 16384
#define EPS2 0.25f
#define EPS4 0.0625f

// Tiling: 256 blocks x 64 ij, full batch per block; 512 thr = 128 b x 4 q
#define TIJ 64
#define NBLK (NIJ / TIJ)        // 256 (1/CU)
#define NTHR 512
#define ROWF 132                // coef row: cA32|cB32|K32|KV32|pad4

// LDS layout (floats)
#define XS_OFF  8448            // X stage [128][36]
#define CC_OFF  13056
#define LAM_OFF 13120
#define LDS_FL  13184           // 52.7 KB
#define STG_ROW 36              // epilogue stage aliases coef region [0,4608)

// part layout per block (packed): num[128][32] @0, den[128] @4096
#define PART_STRIDE 4224
#define DEN_OFF_P 4096

__global__ __launch_bounds__(NTHR, 2) void gmm_fused(
    const float* __restrict__ Xg,
    const float* __restrict__ tptr,
    const float* __restrict__ Mu0, const float* __restrict__ Mu1,
    const float* __restrict__ S0,  const float* __restrict__ S1,
    const float* __restrict__ Lam,
    float* __restrict__ part)
{
    __shared__ __align__(16) float lds[LDS_FL];

    const int tid  = threadIdx.x;
    const int blk  = blockIdx.x;
    const int ij0g = blk * TIJ;
    const float t   = tptr[0];
    const float omt = 1.0f - t;

    // ---- Phase 1a: X full batch -> LDS stage [128][36] (2-way banks) ----
#pragma unroll
    for (int k = 0; k < (BB * ND) / NTHR; ++k) {
        const int idx = tid + k * NTHR;    // 4096 floats
        lds[XS_OFF + (idx >> 5) * STG_ROW + (idx & 31)] = Xg[idx];
    }

    // ---- Phase 1b: per-(ij, n) coefficients into LDS (each exactly once) ----
    // 64 ij * 32 n = 2048 pairs over 512 threads -> 4 each
#pragma unroll
    for (int k = 0; k < (TIJ * ND) / NTHR; ++k) {
        const int idx = tid + k * NTHR;
        const int ijl = idx >> 5;          // 0..63
        const int n   = idx & 31;
        const int ij  = ij0g + ijl;
        const int i   = ij >> 7;
        const int j   = ij & 127;
        const float s0  = S0[i * ND + n];
        const float s1  = S1[j * ND + n];
        const float mu0 = Mu0[i * ND + n];
        const float mu1 = Mu1[j * ND + n];
        const float Ds  = sqrtf(4.0f * s0 * s1 + EPS4);
        const float Cs  = 0.5f * (Ds - EPS2);
        const float Sigma = omt * omt * s0 + t * t * s1
                          + 2.0f * t * omt * Cs + EPS2 * t * omt;
        const float St  = (t * s1 + omt * Cs) - (omt * s0 + t * Cs) - EPS2 * t;
        const float Mut = omt * mu0 + t * mu1;
        const float v   = mu1 - mu0;
        const float invS = 1.0f / Sigma;
        const float Kf  = St * invS;
        const float cA  = -0.5f * invS;
        const float cB  = Mut * invS;
        lds[ijl * ROWF + n]      = cA;
        lds[ijl * ROWF + 32 + n] = cB;
        lds[ijl * ROWF + 64 + n] = Kf;
        lds[ijl * ROWF + 96 + n] = v - Kf * Mut;
        float cc = cA * Mut * Mut - 0.5f * __logf(Sigma);
        cc += __shfl_xor(cc, 1);
        cc += __shfl_xor(cc, 2);
        cc += __shfl_xor(cc, 4);
        cc += __shfl_xor(cc, 8);
        cc += __shfl_xor(cc, 16);
        if (n == 0) lds[CC_OFF + ijl] = cc;
    }
    if (tid < TIJ) lds[LAM_OFF + tid] = Lam[ij0g + tid];

    __syncthreads();

    // ---- X row for this thread's b -> registers (4-lane bcast, 2-way) ----
    const int bl = tid >> 2;      // 0..127 b
    const int q  = tid & 3;       // ij-lane
    float x[ND];
#pragma unroll
    for (int c = 0; c < 8; ++c) {
        const float4 v4 = *(const float4*)&lds[XS_OFF + bl * STG_ROW + 4 * c];
        x[4*c+0] = v4.x; x[4*c+1] = v4.y; x[4*c+2] = v4.z; x[4*c+3] = v4.w;
    }

    float num[ND];
#pragma unroll
    for (int n = 0; n < ND; ++n) num[n] = 0.0f;
    float den = 0.0f;

    // ---- Phase 2: thread does 1 b x 16 ij; row reads are 4-addr bcast ----
#pragma unroll
    for (int it = 0; it < TIJ / 4; ++it) {
        const int ijl = q + it * 4;        // 4 distinct rows/wave, bank-disjoint
        const float* __restrict__ row = &lds[ijl * ROWF];
        const float cc0 = lds[CC_OFF + ijl];
        float lwa = cc0, lwb = 0.0f;
#pragma unroll
        for (int nc = 0; nc < 8; ++nc) {
            const float4 a  = *(const float4*)&row[nc * 4];
            const float4 bq = *(const float4*)&row[32 + nc * 4];
            lwa = fmaf(fmaf(a.x, x[nc*4+0], bq.x), x[nc*4+0], lwa);
            lwb = fmaf(fmaf(a.y, x[nc*4+1], bq.y), x[nc*4+1], lwb);
            lwa = fmaf(fmaf(a.z, x[nc*4+2], bq.z), x[nc*4+2], lwa);
            lwb = fmaf(fmaf(a.w, x[nc*4+3], bq.w), x[nc*4+3], lwb);
        }
        float lw = lwa + lwb;
        lw = fminf(fmaxf(lw, -50.0f), 50.0f);
        const float w = __expf(lw) * lds[LAM_OFF + ijl];
        den += w;
#pragma unroll
        for (int nc = 0; nc < 8; ++nc) {
            const float4 kk = *(const float4*)&row[64 + nc * 4];
            const float4 kv = *(const float4*)&row[96 + nc * 4];
            num[nc*4+0] = fmaf(w, fmaf(kk.x, x[nc*4+0], kv.x), num[nc*4+0]);
            num[nc*4+1] = fmaf(w, fmaf(kk.y, x[nc*4+1], kv.y), num[nc*4+1]);
            num[nc*4+2] = fmaf(w, fmaf(kk.z, x[nc*4+2], kv.z), num[nc*4+2]);
            num[nc*4+3] = fmaf(w, fmaf(kk.w, x[nc*4+3], kv.w), num[nc*4+3]);
        }
    }

    // ---- Reduce across the 4 q-lanes (lane bits 0-1) ----
#pragma unroll
    for (int m = 1; m <= 2; m <<= 1) {
        den += __shfl_xor(den, m);
#pragma unroll
        for (int n = 0; n < ND; ++n) num[n] += __shfl_xor(num[n], m);
    }

    __syncthreads();   // phase-2 LDS reads done before stage overwrites coef

    // ---- Stage into LDS [128][36] rows (2-way banks) ----
    if (q == 0) {
#pragma unroll
        for (int c = 0; c < 8; ++c) {
            *(float4*)&lds[bl * STG_ROW + 4 * c] =
                make_float4(num[4*c], num[4*c+1], num[4*c+2], num[4*c+3]);
        }
        lds[bl * STG_ROW + 32] = den;
    }

    __syncthreads();

    // ---- Coalesced packed block store: 4224 floats, full 128B lines ----
    float* __restrict__ dstg = part + (size_t)blk * PART_STRIDE;
#pragma unroll
    for (int k = 0; k < 3; ++k) {
        const int kk = tid + k * NTHR;     // 1056 float4s used
        if (kk < PART_STRIDE / 4) {
            const int p = 4 * kk;
            float4 val;
            if (p < DEN_OFF_P) {
                val = *(const float4*)&lds[(p >> 5) * STG_ROW + (p & 31)];
            } else {
                const int d = p - DEN_OFF_P;
                val = make_float4(lds[(d + 0) * STG_ROW + 32],
                                  lds[(d + 1) * STG_ROW + 32],
                                  lds[(d + 2) * STG_ROW + 32],
                                  lds[(d + 3) * STG_ROW + 32]);
            }
            *(float4*)(dstg + p) = val;
        }
    }
}

// 256 blocks = (b, n-half). Thread (sg, n16): sums 16 slices; LDS combine.
__global__ __launch_bounds__(256) void gmm_reduce(
    const float* __restrict__ part,
    float* __restrict__ out)
{
    const int blk = blockIdx.x;            // 0..255
    const int b   = blk >> 1;
    const int nh  = blk & 1;
    const int tid = threadIdx.x;
    const int n16 = tid & 15;
    const int sg  = tid >> 4;              // 0..15 slice-groups
    const int n   = nh * 16 + n16;

    float num = 0.0f, den = 0.0f;
#pragma unroll
    for (int g = 0; g < 16; ++g) {
        const int s = sg + g * 16;         // slice 0..255
        const size_t base = (size_t)s * PART_STRIDE;
        num += part[base + b * 32 + n];
        den += part[base + DEN_OFF_P + b]; // same addr across n16 -> broadcast
    }

    __shared__ float red[16][18];
    red[sg][n16] = num;
    if (n16 == 0) red[sg][16] = den;
    __syncthreads();

    if (tid < 16) {
        float ns = 0.0f, ds = 0.0f;
#pragma unroll
        for (int k = 0; k < 16; ++k) {
            ns += red[k][tid];
            ds += red[k][16];
        }
        out[b * 32 + nh * 16 + tid] = ns / ds;
    }
}

extern "C" void kernel_launch(void* const* d_in, const int* in_sizes, int n_in,
                              void* d_out, int out_size, void* d_ws, size_t ws_size,
                              hipStream_t stream)
{
    const float* X   = (const float*)d_in[0];
    const float* t   = (const float*)d_in[1];
    const float* Mu0 = (const float*)d_in[2];
    const float* Mu1 = (const float*)d_in[3];
    const float* S0  = (const float*)d_in[4];
    const float* S1  = (const float*)d_in[5];
    const float* Lam = (const float*)d_in[6];
    float* out  = (float*)d_out;
    float* part = (float*)d_ws;             // NBLK * PART_STRIDE floats (4.3 MB)

    gmm_fused<<<NBLK, NTHR, 0, stream>>>(X, t, Mu0, Mu1, S0, S1, Lam, part);
    gmm_reduce<<<2 * BB, 256, 0, stream>>>(part, out);
}